// Round 2
// baseline (146.585 us; speedup 1.0000x reference)
//
#include <hip/hip_runtime.h>
#include <hip/hip_bf16.h>

typedef __attribute__((ext_vector_type(8))) short short8;
typedef __attribute__((ext_vector_type(4))) float f32x4;

__device__ __forceinline__ unsigned short f32_bf16(float f) {
  unsigned u = __float_as_uint(f);
  u += 0x7fffu + ((u >> 16) & 1u);  // round-to-nearest-even
  return (unsigned short)(u >> 16);
}

// HW packed f32->bf16 (RNE), 1 instr replacing ~10-op software pack.
// dst[15:0] = bf16(lo), dst[31:16] = bf16(hi)
__device__ __forceinline__ unsigned cvt_pk_bf16(float lo, float hi) {
  unsigned r;
  asm("v_cvt_pk_bf16_f32 %0, %1, %2" : "=v"(r) : "v"(lo), "v"(hi));
  return r;
}

__device__ __forceinline__ short8 cvt8(float4 v0, float4 v1) {
  union { unsigned u[4]; short8 s; } f;
  f.u[0] = cvt_pk_bf16(v0.x, v0.y);
  f.u[1] = cvt_pk_bf16(v0.z, v0.w);
  f.u[2] = cvt_pk_bf16(v1.x, v1.y);
  f.u[3] = cvt_pk_bf16(v1.z, v1.w);
  return f.s;
}

// unpack two bf16 pairs, add U+V+b, relu, repack (HW RNE)
__device__ __forceinline__ unsigned addrelu2(unsigned uw, unsigned vw, float blo, float bhi) {
  float ulo = __uint_as_float(uw << 16);
  float uhi = __uint_as_float(uw & 0xffff0000u);
  float vlo = __uint_as_float(vw << 16);
  float vhi = __uint_as_float(vw & 0xffff0000u);
  float slo = ulo + vlo + blo; slo = slo > 0.f ? slo : 0.f;
  float shi = uhi + vhi + bhi; shi = shi > 0.f ? shi : 0.f;
  return cvt_pk_bf16(slo, shi);
}

// DPP row_shr:N add — lane 15 of each 16-lane row ends with the row sum.
template <int CTRL>
__device__ __forceinline__ float dpp_add(float x) {
  int y = __builtin_amdgcn_update_dpp(0, __float_as_int(x), CTRL, 0xf, 0xf, true);
  return x + __int_as_float(y);
}
__device__ __forceinline__ float row_sum16(float x) {
  x = dpp_add<0x118>(x);
  x = dpp_add<0x114>(x);
  x = dpp_add<0x112>(x);
  x = dpp_add<0x111>(x);
  return x;
}

// ---- pass 1: UV[n] = [ Z[n]·W1a , Z[n]·W1b ] in bf16 (256 B per node) ------
// Dense GEMM M=nNodes, N=128, K=128 on 16x16x32 MFMA. W1 B-fragments staged in
// LDS with the column-slot permutation slot(t, col=l15) = feature l15*8+t, so
// each lane's 8 ntile outputs are feature-contiguous -> one uint4 store/row.
// Feature n<64 -> W1 rows 0..127 (src half); n>=64 -> rows 128..255 (dst half).
__global__ __launch_bounds__(256, 2) void uv_kernel(
    const float* __restrict__ z, const float* __restrict__ W1,
    unsigned short* __restrict__ uv, int nNodes) {
  __shared__ unsigned short w1l[32 * 64 * 8];  // 32 KB
  const int tid = threadIdx.x;
  const int wv  = tid >> 6;
  const int l   = tid & 63;
  const int l15 = l & 15;
  const int q   = l >> 4;

#pragma unroll
  for (int pp = 0; pp < 8; ++pp) {
    int p = wv * 8 + pp;       // p = c*8 + t
    int c = p >> 3, t = p & 7;
    short8 f;
#pragma unroll
    for (int j = 0; j < 8; ++j) {
      int k = c * 32 + q * 8 + j;
      int n = l15 * 8 + t;
      int row = (n < 64) ? k : (k + 128);
      f[j] = (short)f32_bf16(W1[row * 64 + (n & 63)]);
    }
    *(short8*)(w1l + (p * 64 + l) * 8) = f;
  }
  __syncthreads();

  const int nTiles = (nNodes + 15) >> 4;
  const int stride = gridDim.x * 4;
  for (int tile = blockIdx.x * 4 + wv; tile < nTiles; tile += stride) {
    int node = tile * 16 + l15;
    node = node < nNodes ? node : nNodes - 1;
    const float* zr = z + (size_t)node * 128;
    short8 a[4];
#pragma unroll
    for (int c = 0; c < 4; ++c) {
      int off = c * 32 + q * 8;
      a[c] = cvt8(*(const float4*)(zr + off), *(const float4*)(zr + off + 4));
    }
    f32x4 acc[8];
#pragma unroll
    for (int t = 0; t < 8; ++t) { acc[t][0] = 0.f; acc[t][1] = 0.f; acc[t][2] = 0.f; acc[t][3] = 0.f; }
#pragma unroll
    for (int c = 0; c < 4; ++c)
#pragma unroll
      for (int t = 0; t < 8; ++t) {
        short8 wf = *(const short8*)(w1l + ((c * 8 + t) * 64 + l) * 8);
        acc[t] = __builtin_amdgcn_mfma_f32_16x16x32_bf16(a[c], wf, acc[t], 0, 0, 0);
      }
    // D[row=q*4+r][col=l15], slot(t,l15) = feature l15*8+t -> natural order
#pragma unroll
    for (int r = 0; r < 4; ++r) {
      int no = tile * 16 + q * 4 + r;
      if (no < nNodes) {
        union { unsigned u[4]; uint4 u4; } pk;
#pragma unroll
        for (int t = 0; t < 4; ++t) pk.u[t] = cvt_pk_bf16(acc[2 * t][r], acc[2 * t + 1][r]);
        *(uint4*)(uv + (size_t)no * 128 + l15 * 8) = pk.u4;
      }
    }
  }
}

// ---- pass 2: per-edge gather UV + relu-add + layers 2,3 + sigmoid -----------
// Latency-bound fix (R this session): grid 2048 (32 waves/CU possible at ~64
// VGPR), 2-deep pipeline: UV gathers for iter+1 issued before computing iter
// (indices prefetched 2 ahead), so a full compute phase covers gather latency.
__global__ __launch_bounds__(256, 4) void lp_edge(
    const unsigned short* __restrict__ uv, const int* __restrict__ ei,
    const float* __restrict__ b1,
    const float* __restrict__ W2, const float* __restrict__ b2,
    const float* __restrict__ W3, const float* __restrict__ b3,
    float* __restrict__ out, int nEdges) {
  const int tid = threadIdx.x;
  const int wv  = tid >> 6;
  const int l   = tid & 63;
  const int l15 = l & 15;
  const int q   = l >> 4;

  short8 w2f[2][2];
#pragma unroll
  for (int c = 0; c < 2; ++c)
#pragma unroll
    for (int t = 0; t < 2; ++t) {
      short8 f;
#pragma unroll
      for (int j = 0; j < 8; ++j)
        f[j] = (short)f32_bf16(W2[(c * 32 + q * 8 + j) * 32 + (t * 16 + l15)]);
      w2f[c][t] = f;
    }
  float bb2[2];
#pragma unroll
  for (int t = 0; t < 2; ++t) bb2[t] = b2[t * 16 + l15];
  const float w3a = W3[l15], w3b = W3[16 + l15], b3v = b3[0];
  float b1f0[8], b1f1[8];
#pragma unroll
  for (int j = 0; j < 8; ++j) { b1f0[j] = b1[q * 8 + j]; b1f1[j] = b1[32 + q * 8 + j]; }

  const int nIter = (nEdges + 15) >> 4;
  const int stride = gridDim.x * 4;
  const int it0 = blockIdx.x * 4 + wv;

  // ---- pipeline prologue ----
  int e0 = it0 * 16 + l15; e0 = e0 < nEdges ? e0 : nEdges - 1;
  int cS = __builtin_nontemporal_load(ei + e0);
  int cD = __builtin_nontemporal_load(ei + nEdges + e0);
  uint4 au0, au1, av0, av1;
  {
    const unsigned short* us = uv + (size_t)cS * 128;        // U half
    const unsigned short* vd = uv + (size_t)cD * 128 + 64;   // V half
    au0 = *(const uint4*)(us + q * 8);
    au1 = *(const uint4*)(us + 32 + q * 8);
    av0 = *(const uint4*)(vd + q * 8);
    av1 = *(const uint4*)(vd + 32 + q * 8);
  }
  int e1 = (it0 + stride) * 16 + l15; e1 = e1 < nEdges ? e1 : nEdges - 1;
  int nS = __builtin_nontemporal_load(ei + e1);
  int nD = __builtin_nontemporal_load(ei + nEdges + e1);

  for (int iter = it0; iter < nIter; iter += stride) {
    // issue NEXT iteration's UV gathers first (covered by this iter's compute)
    const unsigned short* usn = uv + (size_t)nS * 128;
    const unsigned short* vdn = uv + (size_t)nD * 128 + 64;
    uint4 bu0 = *(const uint4*)(usn + q * 8);
    uint4 bu1 = *(const uint4*)(usn + 32 + q * 8);
    uint4 bv0 = *(const uint4*)(vdn + q * 8);
    uint4 bv1 = *(const uint4*)(vdn + 32 + q * 8);
    // prefetch indices two iterations ahead
    int e2 = (iter + 2 * stride) * 16 + l15; e2 = e2 < nEdges ? e2 : nEdges - 1;
    int mS = __builtin_nontemporal_load(ei + e2);
    int mD = __builtin_nontemporal_load(ei + nEdges + e2);

    // h1 fragments: relu(U + V + b1) — computed straight into A-frag layout
    union { unsigned u[4]; short8 s; } f0, f1;
    f0.u[0] = addrelu2(au0.x, av0.x, b1f0[0], b1f0[1]);
    f0.u[1] = addrelu2(au0.y, av0.y, b1f0[2], b1f0[3]);
    f0.u[2] = addrelu2(au0.z, av0.z, b1f0[4], b1f0[5]);
    f0.u[3] = addrelu2(au0.w, av0.w, b1f0[6], b1f0[7]);
    f1.u[0] = addrelu2(au1.x, av1.x, b1f1[0], b1f1[1]);
    f1.u[1] = addrelu2(au1.y, av1.y, b1f1[2], b1f1[3]);
    f1.u[2] = addrelu2(au1.z, av1.z, b1f1[4], b1f1[5]);
    f1.u[3] = addrelu2(au1.w, av1.w, b1f1[6], b1f1[7]);

    // layer 2: [16,64] @ [64,32] + b2
    f32x4 acc2[2];
#pragma unroll
    for (int t = 0; t < 2; ++t) {
      acc2[t][0] = bb2[t]; acc2[t][1] = bb2[t]; acc2[t][2] = bb2[t]; acc2[t][3] = bb2[t];
    }
#pragma unroll
    for (int t = 0; t < 2; ++t) {
      acc2[t] = __builtin_amdgcn_mfma_f32_16x16x32_bf16(f0.s, w2f[0][t], acc2[t], 0, 0, 0);
      acc2[t] = __builtin_amdgcn_mfma_f32_16x16x32_bf16(f1.s, w2f[1][t], acc2[t], 0, 0, 0);
    }

    // layer 3: per-lane partial, DPP row-sum
    float p[4];
#pragma unroll
    for (int r = 0; r < 4; ++r) {
      float h0 = acc2[0][r]; h0 = h0 > 0.f ? h0 : 0.f;
      float h1v = acc2[1][r]; h1v = h1v > 0.f ? h1v : 0.f;
      p[r] = row_sum16(h0 * w3a + h1v * w3b);
    }

    if (l15 == 15) {
      int eb = iter * 16 + q * 4;
      f32x4 o;
      o[0] = 1.f / (1.f + __expf(-(p[0] + b3v)));
      o[1] = 1.f / (1.f + __expf(-(p[1] + b3v)));
      o[2] = 1.f / (1.f + __expf(-(p[2] + b3v)));
      o[3] = 1.f / (1.f + __expf(-(p[3] + b3v)));
      if (eb + 3 < nEdges) {
        __builtin_nontemporal_store(o, (f32x4*)(out + eb));
      } else {
        if (eb < nEdges)     out[eb]     = o[0];
        if (eb + 1 < nEdges) out[eb + 1] = o[1];
        if (eb + 2 < nEdges) out[eb + 2] = o[2];
      }
    }

    // rotate pipeline registers
    au0 = bu0; au1 = bu1; av0 = bv0; av1 = bv1;
    nS = mS; nD = mD;
  }
}

// ---- correctness-only fallback (ws too small; never expected) ---------------
__global__ void lp_naive(const float* __restrict__ z, const int* __restrict__ ei,
                         const float* __restrict__ W1, const float* __restrict__ b1,
                         const float* __restrict__ W2, const float* __restrict__ b2,
                         const float* __restrict__ W3, const float* __restrict__ b3,
                         float* __restrict__ out, int nEdges) {
  int e = blockIdx.x * 256 + threadIdx.x;
  if (e >= nEdges) return;
  int s = ei[e], d = ei[nEdges + e];
  float h1[64], h2[32];
  for (int k = 0; k < 64; ++k) {
    float a = b1[k];
    for (int i = 0; i < 128; ++i) a += z[(size_t)s * 128 + i] * W1[i * 64 + k];
    for (int i = 0; i < 128; ++i) a += z[(size_t)d * 128 + i] * W1[(128 + i) * 64 + k];
    h1[k] = a > 0.f ? a : 0.f;
  }
  for (int k = 0; k < 32; ++k) {
    float a = b2[k];
    for (int i = 0; i < 64; ++i) a += h1[i] * W2[i * 32 + k];
    h2[k] = a > 0.f ? a : 0.f;
  }
  float lg = b3[0];
  for (int i = 0; i < 32; ++i) lg += h2[i] * W3[i];
  out[e] = 1.f / (1.f + __expf(-lg));
}

extern "C" void kernel_launch(void* const* d_in, const int* in_sizes, int n_in,
                              void* d_out, int out_size, void* d_ws, size_t ws_size,
                              hipStream_t stream) {
  const float* z  = (const float*)d_in[0];
  const int* ei   = (const int*)d_in[1];
  const float* W1 = (const float*)d_in[2];
  const float* b1 = (const float*)d_in[3];
  const float* W2 = (const float*)d_in[4];
  const float* b2 = (const float*)d_in[5];
  const float* W3 = (const float*)d_in[6];
  const float* b3 = (const float*)d_in[7];
  float* out = (float*)d_out;

  const int nZ = in_sizes[0];
  const int nNodes = nZ / 128;
  const int nEdges = in_sizes[1] / 2;

  if (ws_size >= (size_t)nNodes * 128 * sizeof(unsigned short)) {
    unsigned short* uvp = (unsigned short*)d_ws;
    // uv: each wave does exactly ceil(nTiles/waves)=2 tiles -> balanced tail
    int nTiles = (nNodes + 15) >> 4;
    int uvGrid = (nTiles + 7) >> 3;               // 2 tiles per wave
    if (uvGrid > 1024) uvGrid = 1024;
    uv_kernel<<<uvGrid, 256, 0, stream>>>(z, W1, uvp, nNodes);
    lp_edge<<<2048, 256, 0, stream>>>(uvp, ei, b1, W2, b2, W3, b3, out, nEdges);
  } else {
    lp_naive<<<(nEdges + 255) / 256, 256, 0, stream>>>(z, ei, W1, b1, W2, b2, W3, b3, out, nEdges);
  }
}